// Round 1
// baseline (141.583 us; speedup 1.0000x reference)
//
#include <hip/hip_runtime.h>
#include <math.h>

#define S 255
#define B 4

typedef _Float16 half8 __attribute__((ext_vector_type(8)));
typedef float f32x4 __attribute__((ext_vector_type(4)));

// ---- workspace layout (float offsets) ----
// frag layout for a 256x256 (row r, k) f16 matrix:
//   addr(r,k) = ((rt*8 + ks)*64 + (r&15) + 16*((k>>3)&3))*8 + (k&7)
#define WS_APJ   0          // f16[4][65536]  A' frag, row j = A'[j-1], j=0 zeroed
#define WS_BPJ   131072     // f16[4][65536]  B' frag, j-shifted
#define WS_VTF   262144     // f16[4][65536]  V^T frag: (col d, k=j)
#define WS_AP    393216     // f32[1020][256] row-major A'
#define WS_MFG   654336     // f16[4096] M in B-frag order
#define WS_CONST 656384     // f32[8]
#define WS_QLOG  656392     // f32[4][8][256]
#define WS_KLOG  664584     // f32[4][8][256]  (ends 672776)
#define WS_ST    673792     // f32x2[4][256][256] (inv, -mu*inv)  (ends 1198080)

__device__ __forceinline__ half8 cvt8(float4 a, float4 b) {
    half8 h;
    h[0]=(_Float16)a.x; h[1]=(_Float16)a.y; h[2]=(_Float16)a.z; h[3]=(_Float16)a.w;
    h[4]=(_Float16)b.x; h[5]=(_Float16)b.y; h[6]=(_Float16)b.z; h[7]=(_Float16)b.w;
    return h;
}

// ===========================================================================
// K1: 0..63 V->VTF | 64..127 A' | 128..191 B' | 192..207 qklog | 208 misc
// ===========================================================================
__global__ __launch_bounds__(256) void k1(
    const float* __restrict__ desc, const float* __restrict__ nve,
    const float* __restrict__ qW, const float* __restrict__ qb,
    const float* __restrict__ kW, const float* __restrict__ kb,
    const float* __restrict__ vW, const float* __restrict__ vb,
    const float* __restrict__ eW1, const float* __restrict__ eb1,
    const float* __restrict__ eW2, const float* __restrict__ eb2,
    const float* __restrict__ aW, float* __restrict__ ws)
{
    const int blk = blockIdx.x;
    const int tid = threadIdx.x;
    __shared__ _Float16 Af[4096];
    __shared__ _Float16 Bf[4096];
    const int wave = tid >> 6, lane = tid & 63;
    const int m16 = lane & 15, quad = lane >> 4;
    const int sr = tid & 63, sko = (tid >> 6) * 16;
    const half8 z8 = {(_Float16)0,(_Float16)0,(_Float16)0,(_Float16)0,
                      (_Float16)0,(_Float16)0,(_Float16)0,(_Float16)0};

    if (blk < 192) {
        const float *X, *W; int M, wst, wof, jobt, sub = blk;
        if (sub < 64)       { X=nve;  W=vW;  M=1024; wst=256; wof=0;   jobt=0; }
        else if (sub < 128) { X=desc; W=eW1; M=1020; wst=512; wof=0;   jobt=1; sub-=64; }
        else                { X=desc; W=eW1; M=1020; wst=512; wof=256; jobt=2; sub-=128; }
        int mBase = (sub>>2)*64, nBase = (sub&3)*64;
        f32x4 acc[2][2] = {};
        for (int k0 = 0; k0 < 256; k0 += 64) {
            half8 xa[2], wb[2];
            int xr = mBase + sr, wr = nBase + sr;
            #pragma unroll
            for (int hh = 0; hh < 2; hh++) {
                int kk = k0 + sko + hh*8;
                if (xr < M) xa[hh] = cvt8(*(const float4*)&X[xr*256 + kk],
                                          *(const float4*)&X[xr*256 + kk + 4]);
                else xa[hh] = z8;
                wb[hh] = cvt8(*(const float4*)&W[wr*wst + wof + kk],
                              *(const float4*)&W[wr*wst + wof + kk + 4]);
            }
            __syncthreads();
            #pragma unroll
            for (int hh = 0; hh < 2; hh++) {
                int krel = sko + hh*8;
                int c = krel >> 5, q2 = (krel >> 3) & 3;
                int ld = (sr & 15) + 16*q2, rt = sr >> 4;
                *(half8*)&Af[((rt*2 + c)*64 + ld)*8] = xa[hh];
                *(half8*)&Bf[((rt*2 + c)*64 + ld)*8] = wb[hh];
            }
            __syncthreads();
            int rt0 = (wave >> 1)*2, ct0 = (wave & 1)*2;
            #pragma unroll
            for (int c = 0; c < 2; c++) {
                half8 A0 = *(const half8*)&Af[(((rt0    )*2 + c)*64 + lane)*8];
                half8 A1 = *(const half8*)&Af[(((rt0 + 1)*2 + c)*64 + lane)*8];
                half8 B0 = *(const half8*)&Bf[(((ct0    )*2 + c)*64 + lane)*8];
                half8 B1 = *(const half8*)&Bf[(((ct0 + 1)*2 + c)*64 + lane)*8];
                acc[0][0] = __builtin_amdgcn_mfma_f32_16x16x32_f16(A0, B0, acc[0][0], 0,0,0);
                acc[0][1] = __builtin_amdgcn_mfma_f32_16x16x32_f16(A0, B1, acc[0][1], 0,0,0);
                acc[1][0] = __builtin_amdgcn_mfma_f32_16x16x32_f16(A1, B0, acc[1][0], 0,0,0);
                acc[1][1] = __builtin_amdgcn_mfma_f32_16x16x32_f16(A1, B1, acc[1][1], 0,0,0);
            }
        }
        int rt0 = (wave >> 1)*2, ct0 = (wave & 1)*2;
        if (jobt == 0) {
            _Float16* vtf = (_Float16*)(ws + WS_VTF);
            #pragma unroll
            for (int ci = 0; ci < 2; ci++) {
                int col = nBase + (ct0 + ci)*16 + m16;
                float bv = vb[col];
                int ct = col >> 4, n = col & 15;
                #pragma unroll
                for (int ri = 0; ri < 2; ri++)
                    #pragma unroll
                    for (int r = 0; r < 4; r++) {
                        int rr = mBase + (rt0 + ri)*16 + quad*4 + r;
                        int bb = rr >> 8, j = rr & 255;
                        int js = j >> 5, qv = (j >> 3) & 3, ev = j & 7;
                        float o = acc[ri][ci][r] + bv;
                        vtf[bb*65536 + (((ct*8 + js)*64 + n + 16*qv) << 3) + ev] = (_Float16)o;
                    }
            }
        } else {
            _Float16* OJ = (_Float16*)(ws + ((jobt == 1) ? WS_APJ : WS_BPJ));
            #pragma unroll
            for (int ci = 0; ci < 2; ci++) {
                int col = nBase + (ct0 + ci)*16 + m16;
                float bv = (jobt == 1) ? eb1[col] : 0.f;
                int ks = col >> 5, q = (col >> 3) & 3, e = col & 7;
                #pragma unroll
                for (int ri = 0; ri < 2; ri++)
                    #pragma unroll
                    for (int r = 0; r < 4; r++) {
                        int rr = mBase + (rt0 + ri)*16 + quad*4 + r;
                        if (rr < 1020) {
                            float o = acc[ri][ci][r] + bv;
                            int bb = rr / 255;
                            int j = rr - bb*255 + 1;
                            int jt = j >> 4, mm = j & 15;
                            OJ[bb*65536 + (((jt*8 + ks)*64 + mm + 16*q) << 3) + e] = (_Float16)o;
                            if (jobt == 1) ws[WS_AP + rr*256 + col] = o;
                        }
                    }
            }
        }
    } else if (blk < 208) {
        // qklog = nve @ fold (fold in Bf)
        {
            int d = tid;
            float f[16] = {0,0,0,0,0,0,0,0,0,0,0,0,0,0,0,0};
            for (int hd = 0; hd < 32; hd++) {
                float wq = aW[hd], wk = aW[32+hd];
                #pragma unroll
                for (int h = 0; h < 8; h++) {
                    f[h]   = fmaf(wq, qW[(h*32+hd)*256 + d], f[h]);
                    f[8+h] = fmaf(wk, kW[(h*32+hd)*256 + d], f[8+h]);
                }
            }
            int ksd = d >> 5, q2 = (d >> 3) & 3, jj = d & 7;
            #pragma unroll
            for (int n = 0; n < 16; n++)
                Bf[((ksd*64 + n + 16*q2))*8 + jj] = (_Float16)f[n];
        }
        __syncthreads();
        int mBase = (blk - 192)*64;
        f32x4 acc = {0.f,0.f,0.f,0.f};
        for (int k0 = 0; k0 < 256; k0 += 64) {
            half8 xa[2];
            #pragma unroll
            for (int hh = 0; hh < 2; hh++) {
                int kk = k0 + sko + hh*8;
                xa[hh] = cvt8(*(const float4*)&nve[(mBase + sr)*256 + kk],
                              *(const float4*)&nve[(mBase + sr)*256 + kk + 4]);
            }
            __syncthreads();
            #pragma unroll
            for (int hh = 0; hh < 2; hh++) {
                int krel = sko + hh*8;
                int c = krel >> 5, q2 = (krel >> 3) & 3;
                int ld = (sr & 15) + 16*q2, rt = sr >> 4;
                *(half8*)&Af[((rt*2 + c)*64 + ld)*8] = xa[hh];
            }
            __syncthreads();
            #pragma unroll
            for (int c = 0; c < 2; c++) {
                half8 A  = *(const half8*)&Af[((wave*2 + c)*64 + lane)*8];
                half8 Bv = *(const half8*)&Bf[(((k0 >> 5) + c)*64 + lane)*8];
                acc = __builtin_amdgcn_mfma_f32_16x16x32_f16(A, Bv, acc, 0,0,0);
            }
        }
        #pragma unroll
        for (int r = 0; r < 4; r++) {
            int rr = mBase + wave*16 + quad*4 + r;
            int bb = rr >> 8, tt2 = rr & 255;
            if (m16 < 8) ws[WS_QLOG + (bb*8 + m16)*256 + tt2] = acc[r];
            else         ws[WS_KLOG + (bb*8 + m16 - 8)*256 + tt2] = acc[r];
        }
    } else {
        // misc: MFG + CONST + zero j=0 frag rows
        _Float16* mfg = (_Float16*)(ws + WS_MFG);
        int k = tid;
        float a8[8] = {0,0,0,0,0,0,0,0};
        for (int hd = 0; hd < 32; hd++) {
            float we = aW[64+hd];
            #pragma unroll
            for (int h = 0; h < 8; h++)
                a8[h] = fmaf(we, eW2[(h*32+hd)*256 + k], a8[h]);
        }
        int ksd = k >> 5, q2 = (k >> 3) & 3, jj = k & 7;
        #pragma unroll
        for (int h = 0; h < 8; h++)
            mfg[((ksd*64 + h + 16*q2))*8 + jj] = (_Float16)a8[h];
        #pragma unroll
        for (int n = 8; n < 16; n++)
            mfg[((ksd*64 + n + 16*q2))*8 + jj] = (_Float16)0.f;
        {
            _Float16* apj = (_Float16*)(ws + WS_APJ);
            _Float16* bpj = (_Float16*)(ws + WS_BPJ);
            int ks0 = tid >> 5, qz = (tid >> 3) & 3, ez = tid & 7;
            int ad = ((ks0*64 + 16*qz) << 3) + ez;
            #pragma unroll
            for (int bb = 0; bb < 4; bb++) {
                apj[bb*65536 + ad] = (_Float16)0.f;
                bpj[bb*65536 + ad] = (_Float16)0.f;
            }
        }
        if (tid == 0) {
            #pragma unroll
            for (int h = 0; h < 8; h++) {
                float c = 0.f;
                for (int hd = 0; hd < 32; hd++) {
                    c = fmaf(aW[64+hd], eb2[h*32+hd], c);
                    c = fmaf(aW[hd],    qb [h*32+hd], c);
                    c = fmaf(aW[32+hd], kb [h*32+hd], c);
                }
                ws[WS_CONST + h] = c;
            }
        }
    }
}

// ===========================================================================
// K2: LN-stat precompute. grid (16,4) x 256.
// Block (rt,b): apj rows rt*16..rt*16+15  x  all 256 j.
//   G = Apj @ Bpj^T (MFMA, full 16-row tiles), SB/QB per j via f16 MFMA
//   (bit-identical to old k3 phase A math), SA/QA per i from f32 WS_AP.
//   Writes ST[b][i][j] = (inv, -mu*inv).  Row i=0 = diagonal stats (i==j).
// ===========================================================================
__global__ __launch_bounds__(256) void k2(float* __restrict__ ws)
{
    const int rt = blockIdx.x, b = blockIdx.y;
    const int tid = threadIdx.x;
    const int wave = tid >> 6, lane = tid & 63;
    const int m16 = lane & 15, quad = lane >> 4;
    __shared__ float saL[16], qaL[16], qbL[256];

    const _Float16* bpj = (const _Float16*)(ws + WS_BPJ) + b*65536;
    const _Float16* apj = (const _Float16*)(ws + WS_APJ) + b*65536;
    float2* ST = (float2*)(ws + WS_ST) + b*65536;

    half8 ones8;
    #pragma unroll
    for (int e = 0; e < 8; e++) ones8[e] = (_Float16)1.0f;

    // f32 SA/QA for the block's 16 apj rows (apj row i = A'[i-1], row 0 = zeros)
    {
        int i_loc = wave*4;  // wave handles 4 rows
        #pragma unroll
        for (int rr = 0; rr < 4; rr++) {
            int il = i_loc + rr;
            int i = rt*16 + il;
            float s = 0.f, q = 0.f;
            if (i >= 1) {
                float4 v = *(const float4*)&ws[WS_AP + ((size_t)(b*S + i - 1))*256 + lane*4];
                s = v.x + v.y + v.z + v.w;
                q = v.x*v.x + v.y*v.y + v.z*v.z + v.w*v.w;
            }
            #pragma unroll
            for (int off = 32; off >= 1; off >>= 1) {
                s += __shfl_xor(s, off, 64);
                q += __shfl_xor(q, off, 64);
            }
            if (lane == 0) { saL[il] = s; qaL[il] = q; }
        }
    }

    // SB/QB for this wave's 4 j-tiles
    float sbR[4];
    #pragma unroll
    for (int jt4 = 0; jt4 < 4; jt4++) {
        int jt = wave*4 + jt4;
        f32x4 accS = {}, accQ = {};
        #pragma unroll
        for (int ks = 0; ks < 8; ks++) {
            half8 bb = *(const half8*)&bpj[((jt*8 + ks)*64 + lane) << 3];
            accS = __builtin_amdgcn_mfma_f32_16x16x32_f16(ones8, bb, accS, 0,0,0);
            accQ = __builtin_amdgcn_mfma_f32_16x16x32_f16(bb, bb, accQ, 0,0,0);
        }
        sbR[jt4] = accS[0];                       // SB[jt*16+m16] (all rows equal)
        if (quad == (m16 >> 2)) qbL[jt*16 + m16] = accQ[m16 & 3];   // diag
    }
    __syncthreads();

    // G tile rows + st epilogue
    half8 aa[8];
    #pragma unroll
    for (int ks = 0; ks < 8; ks++)
        aa[ks] = *(const half8*)&apj[((rt*8 + ks)*64 + lane) << 3];

    #pragma unroll
    for (int jt4 = 0; jt4 < 4; jt4++) {
        int jt = wave*4 + jt4;
        f32x4 acc = {};
        #pragma unroll
        for (int ks = 0; ks < 8; ks++) {
            half8 bb = *(const half8*)&bpj[((jt*8 + ks)*64 + lane) << 3];
            acc = __builtin_amdgcn_mfma_f32_16x16x32_f16(aa[ks], bb, acc, 0,0,0);
        }
        int j = jt*16 + m16;
        float sb = sbR[jt4], qbv = qbL[j];
        #pragma unroll
        for (int r = 0; r < 4; r++) {
            int il = quad*4 + r;
            int i = rt*16 + il;
            float sa = saL[il], qa = qaL[il];
            float mu  = (sa + sb) * (1.0f/256.0f);
            float var = (qa + qbv + 2.f*acc[r]) * (1.0f/256.0f) - mu*mu;
            float inv = rsqrtf(var + 1e-5f);
            float2 o;
            if (j == 0) { o.x = 0.f; o.y = 0.f; }
            else        { o.x = inv; o.y = -mu*inv; }
            if (i >= 1) {
                ST[i*256 + j] = o;
                if (i == j) ST[j] = o;    // row i=0 (cls) uses diag stats
            }
        }
    }
    if (rt == 0 && tid == 0) { float2 z; z.x = 0.f; z.y = 0.f; ST[0] = z; }
}

// ===========================================================================
// K3: logits (MFMA) + softmax + attn + ctx (MFMA). st precomputed by k2.
// grid (256,4) x 256
// ===========================================================================
#define PLS 272

__global__ __launch_bounds__(256, 4) void k3(
    const float* __restrict__ ln_g, const float* __restrict__ ln_b,
    const float* __restrict__ ab, const float* __restrict__ ws,
    float* __restrict__ out)
{
    int b = blockIdx.y, i = blockIdx.x;
    int tid = threadIdx.x;
    __shared__ float klds[2048];
    __shared__ float PL[8*PLS];
    __shared__ float gL[256], bL[256], aL[256];
    __shared__ float2 st[256];
    __shared__ float baseh[8], sms[8];

    int wave = tid >> 6, lane = tid & 63;
    int m16 = lane & 15, quad = lane >> 4;
    const half8 z8 = {(_Float16)0,(_Float16)0,(_Float16)0,(_Float16)0,
                      (_Float16)0,(_Float16)0,(_Float16)0,(_Float16)0};

    #pragma unroll
    for (int t = 0; t < 8; t++)
        klds[tid + t*256] = ws[WS_KLOG + b*2048 + tid + t*256];
    gL[tid] = ln_g[tid];
    bL[tid] = ln_b[tid];
    aL[tid] = (i >= 1) ? ws[WS_AP + ((size_t)(b*S + i - 1))*256 + tid] : 0.f;
    st[tid] = ((const float2*)(ws + WS_ST))[(((size_t)b*256 + i) << 8) + tid];
    if (tid < 8)
        baseh[tid] = ws[WS_QLOG + (b*8+tid)*256 + i] + ab[0] + ws[WS_CONST + tid];
    __syncthreads();

    const _Float16* mfg = (const _Float16*)(ws + WS_MFG);
    const _Float16* bpj = (const _Float16*)(ws + WS_BPJ) + b*65536;
    const _Float16* apj = (const _Float16*)(ws + WS_APJ) + b*65536;
    const _Float16* vtf = (const _Float16*)(ws + WS_VTF) + b*65536;

    // ---- logits MFMA ----
    f32x4 acc[4] = {};
    float2 sv[4];
    #pragma unroll
    for (int tt = 0; tt < 4; tt++)
        sv[tt] = st[(wave*4 + tt)*16 + m16];

    if (i >= 1) {
        #pragma unroll
        for (int ks = 0; ks < 8; ks++) {
            int k = ks*32 + quad*8;
            float4 a0 = *(const float4*)&aL[k], a1 = *(const float4*)&aL[k+4];
            float4 g0 = *(const float4*)&gL[k], g1 = *(const float4*)&gL[k+4];
            float4 b0 = *(const float4*)&bL[k], b1 = *(const float4*)&bL[k+4];
            half8 bf = *(const half8*)&mfg[(ks*64 + lane) << 3];
            float aa[8] = {a0.x,a0.y,a0.z,a0.w,a1.x,a1.y,a1.z,a1.w};
            float ga[8] = {g0.x,g0.y,g0.z,g0.w,g1.x,g1.y,g1.z,g1.w};
            float be[8] = {b0.x,b0.y,b0.z,b0.w,b1.x,b1.y,b1.z,b1.w};
            #pragma unroll
            for (int tt = 0; tt < 4; tt++) {
                half8 bp = *(const half8*)&bpj[(((wave*4 + tt)*8 + ks)*64 + lane) << 3];
                half8 af;
                #pragma unroll
                for (int e = 0; e < 8; e++) {
                    float c = (float)bp[e] + aa[e];
                    float w = fmaf(fmaf(c, sv[tt].x, sv[tt].y), ga[e], be[e]);
                    af[e] = (_Float16)fmaxf(w, 0.f);
                }
                acc[tt] = __builtin_amdgcn_mfma_f32_16x16x32_f16(af, bf, acc[tt], 0,0,0);
            }
        }
    } else {
        #pragma unroll
        for (int ks = 0; ks < 8; ks++) {
            int k = ks*32 + quad*8;
            float4 g0 = *(const float4*)&gL[k], g1 = *(const float4*)&gL[k+4];
            float4 b0 = *(const float4*)&bL[k], b1 = *(const float4*)&bL[k+4];
            half8 bf = *(const half8*)&mfg[(ks*64 + lane) << 3];
            float ga[8] = {g0.x,g0.y,g0.z,g0.w,g1.x,g1.y,g1.z,g1.w};
            float be[8] = {b0.x,b0.y,b0.z,b0.w,b1.x,b1.y,b1.z,b1.w};
            #pragma unroll
            for (int tt = 0; tt < 4; tt++) {
                int idx = ((((wave*4 + tt)*8 + ks)*64 + lane) << 3);
                half8 bp = *(const half8*)&bpj[idx];
                half8 ap = *(const half8*)&apj[idx];
                half8 af;
                #pragma unroll
                for (int e = 0; e < 8; e++) {
                    float c = (float)ap[e] + (float)bp[e];
                    float w = fmaf(fmaf(c, sv[tt].x, sv[tt].y), ga[e], be[e]);
                    af[e] = (_Float16)fmaxf(w, 0.f);
                }
                acc[tt] = __builtin_amdgcn_mfma_f32_16x16x32_f16(af, bf, acc[tt], 0,0,0);
            }
        }
    }

    if (m16 < 8) {
        float basev = baseh[m16];
        #pragma unroll
        for (int tt = 0; tt < 4; tt++)
            #pragma unroll
            for (int r = 0; r < 4; r++) {
                int jr = (wave*4 + tt)*16 + quad*4 + r;
                float val = basev + klds[m16*256 + jr];
                val += (jr == 0) ? -1e9f : acc[tt][r];
                PL[m16*PLS + jr] = val;
            }
    }
    __syncthreads();

    // ---- softmax: wave w owns heads 2w, 2w+1 (no block-wide reductions) ----
    float* attnOut = out + 262144;
    #pragma unroll
    for (int hh = 0; hh < 2; hh++) {
        int h = wave*2 + hh;
        float4 v = *(const float4*)&PL[h*PLS + lane*4];
        float mv = fmaxf(fmaxf(v.x, v.y), fmaxf(v.z, v.w));
        #pragma unroll
        for (int off = 32; off >= 1; off >>= 1)
            mv = fmaxf(mv, __shfl_xor(mv, off, 64));
        float4 p;
        p.x = __expf(v.x - mv); p.y = __expf(v.y - mv);
        p.z = __expf(v.z - mv); p.w = __expf(v.w - mv);
        float s = p.x + p.y + p.z + p.w;
        #pragma unroll
        for (int off = 32; off >= 1; off >>= 1)
            s += __shfl_xor(s, off, 64);
        *(float4*)&PL[h*PLS + lane*4] = p;
        if (lane == 0) sms[h] = s;
        float rs = 1.0f / s;
        float4 ao;
        ao.x = p.x*rs; ao.y = p.y*rs; ao.z = p.z*rs; ao.w = p.w*rs;
        *(float4*)&attnOut[((b*8+h)*256 + i)*256 + lane*4] = ao;
    }
    __syncthreads();

    // ---- ctx via MFMA: A rows = heads of p, B = VTF frags ----
    {
        f32x4 cacc[4] = {};
        int ct0 = wave*4;
        #pragma unroll
        for (int js = 0; js < 8; js++) {
            half8 af;
            if (m16 < 8) {
                float4 p0 = *(const float4*)&PL[m16*PLS + js*32 + quad*8];
                float4 p1 = *(const float4*)&PL[m16*PLS + js*32 + quad*8 + 4];
                af = cvt8(p0, p1);
            } else af = z8;
            #pragma unroll
            for (int cl = 0; cl < 4; cl++) {
                half8 bf = *(const half8*)&vtf[(((ct0+cl)*8 + js)*64 + lane) << 3];
                cacc[cl] = __builtin_amdgcn_mfma_f32_16x16x32_f16(af, bf, cacc[cl], 0,0,0);
            }
        }
        #pragma unroll
        for (int cl = 0; cl < 4; cl++) {
            int ct = ct0 + cl;
            int h = ct >> 1;
            if (quad == (h >> 2)) {
                float rs = 1.0f / sms[h];
                out[(b*256 + i)*256 + ct*16 + m16] = cacc[cl][h & 3] * rs;
            }
        }
    }
}

// ---------------------------------------------------------------------------
extern "C" void kernel_launch(void* const* d_in, const int* in_sizes, int n_in,
                              void* d_out, int out_size, void* d_ws, size_t ws_size,
                              hipStream_t stream)
{
    const float* desc = (const float*)d_in[0];
    const float* nve  = (const float*)d_in[1];
    const float* qW   = (const float*)d_in[2];
    const float* qb   = (const float*)d_in[3];
    const float* kW   = (const float*)d_in[4];
    const float* kb   = (const float*)d_in[5];
    const float* vW   = (const float*)d_in[6];
    const float* vb   = (const float*)d_in[7];
    const float* eW1  = (const float*)d_in[8];
    const float* eb1  = (const float*)d_in[9];
    const float* ln_g = (const float*)d_in[10];
    const float* ln_b = (const float*)d_in[11];
    const float* eW2  = (const float*)d_in[12];
    const float* eb2  = (const float*)d_in[13];
    const float* aW   = (const float*)d_in[14];
    const float* ab   = (const float*)d_in[15];
    float* ws  = (float*)d_ws;
    float* out = (float*)d_out;

    k1<<<dim3(209), 256, 0, stream>>>(desc, nve, qW, qb, kW, kb, vW, vb,
                                      eW1, eb1, eW2, eb2, aW, ws);
    k2<<<dim3(16, 4), 256, 0, stream>>>(ws);
    k3<<<dim3(256, 4), 256, 0, stream>>>(ln_g, ln_b, ab, ws, out);
}

// Round 4
// 125.926 us; speedup vs baseline: 1.1243x; 1.1243x over previous
//
#include <hip/hip_runtime.h>
#include <math.h>

#define S 255
#define B 4

typedef _Float16 half8 __attribute__((ext_vector_type(8)));
typedef float f32x4 __attribute__((ext_vector_type(4)));

// ---- workspace layout (float offsets) ----
#define WS_APJ   0          // f16[4][65536]  A' frag, row j = A'[j-1], j=0 zeroed
#define WS_BPJ   131072     // f16[4][65536]  B' frag, j-shifted
#define WS_VTF   262144     // f16[4][65536]  V^T frag: (col d, k=j)
#define WS_AP    393216     // f32[1020][256] row-major A'
#define WS_MFG   654336     // f16[4096] M in B-frag order
#define WS_CONST 656384     // f32[8]
#define WS_QLOG  656392     // f32[4][8][256]
#define WS_KLOG  664584     // f32[4][8][256]  (ends 672776)

#define PLS 272

__device__ __forceinline__ half8 cvt8(float4 a, float4 b) {
    half8 h;
    h[0]=(_Float16)a.x; h[1]=(_Float16)a.y; h[2]=(_Float16)a.z; h[3]=(_Float16)a.w;
    h[4]=(_Float16)b.x; h[5]=(_Float16)b.y; h[6]=(_Float16)b.z; h[7]=(_Float16)b.w;
    return h;
}

// ===========================================================================
// K1: 0..63 V->VTF | 64..127 A' | 128..191 B' | 192..207 qklog | 208 misc
// (verified R0 body; CONST parallelized)
// ===========================================================================
__global__ __launch_bounds__(256) void k1(
    const float* __restrict__ desc, const float* __restrict__ nve,
    const float* __restrict__ qW, const float* __restrict__ qb,
    const float* __restrict__ kW, const float* __restrict__ kb,
    const float* __restrict__ vW, const float* __restrict__ vb,
    const float* __restrict__ eW1, const float* __restrict__ eb1,
    const float* __restrict__ eW2, const float* __restrict__ eb2,
    const float* __restrict__ aW, float* __restrict__ ws)
{
    const int blk = blockIdx.x;
    const int tid = threadIdx.x;
    __shared__ _Float16 Af[4096];
    __shared__ _Float16 Bf[4096];
    const int wave = tid >> 6, lane = tid & 63;
    const int m16 = lane & 15, quad = lane >> 4;
    const int sr = tid & 63, sko = (tid >> 6) * 16;
    const half8 z8 = {(_Float16)0,(_Float16)0,(_Float16)0,(_Float16)0,
                      (_Float16)0,(_Float16)0,(_Float16)0,(_Float16)0};

    if (blk < 192) {
        const float *X, *W; int M, wst, wof, jobt, sub = blk;
        if (sub < 64)       { X=nve;  W=vW;  M=1024; wst=256; wof=0;   jobt=0; }
        else if (sub < 128) { X=desc; W=eW1; M=1020; wst=512; wof=0;   jobt=1; sub-=64; }
        else                { X=desc; W=eW1; M=1020; wst=512; wof=256; jobt=2; sub-=128; }
        int mBase = (sub>>2)*64, nBase = (sub&3)*64;
        f32x4 acc[2][2] = {};
        for (int k0 = 0; k0 < 256; k0 += 64) {
            half8 xa[2], wb[2];
            int xr = mBase + sr, wr = nBase + sr;
            #pragma unroll
            for (int hh = 0; hh < 2; hh++) {
                int kk = k0 + sko + hh*8;
                if (xr < M) xa[hh] = cvt8(*(const float4*)&X[xr*256 + kk],
                                          *(const float4*)&X[xr*256 + kk + 4]);
                else xa[hh] = z8;
                wb[hh] = cvt8(*(const float4*)&W[wr*wst + wof + kk],
                              *(const float4*)&W[wr*wst + wof + kk + 4]);
            }
            __syncthreads();
            #pragma unroll
            for (int hh = 0; hh < 2; hh++) {
                int krel = sko + hh*8;
                int c = krel >> 5, q2 = (krel >> 3) & 3;
                int ld = (sr & 15) + 16*q2, rt = sr >> 4;
                *(half8*)&Af[((rt*2 + c)*64 + ld)*8] = xa[hh];
                *(half8*)&Bf[((rt*2 + c)*64 + ld)*8] = wb[hh];
            }
            __syncthreads();
            int rt0 = (wave >> 1)*2, ct0 = (wave & 1)*2;
            #pragma unroll
            for (int c = 0; c < 2; c++) {
                half8 A0 = *(const half8*)&Af[(((rt0    )*2 + c)*64 + lane)*8];
                half8 A1 = *(const half8*)&Af[(((rt0 + 1)*2 + c)*64 + lane)*8];
                half8 B0 = *(const half8*)&Bf[(((ct0    )*2 + c)*64 + lane)*8];
                half8 B1 = *(const half8*)&Bf[(((ct0 + 1)*2 + c)*64 + lane)*8];
                acc[0][0] = __builtin_amdgcn_mfma_f32_16x16x32_f16(A0, B0, acc[0][0], 0,0,0);
                acc[0][1] = __builtin_amdgcn_mfma_f32_16x16x32_f16(A0, B1, acc[0][1], 0,0,0);
                acc[1][0] = __builtin_amdgcn_mfma_f32_16x16x32_f16(A1, B0, acc[1][0], 0,0,0);
                acc[1][1] = __builtin_amdgcn_mfma_f32_16x16x32_f16(A1, B1, acc[1][1], 0,0,0);
            }
        }
        int rt0 = (wave >> 1)*2, ct0 = (wave & 1)*2;
        if (jobt == 0) {
            _Float16* vtf = (_Float16*)(ws + WS_VTF);
            #pragma unroll
            for (int ci = 0; ci < 2; ci++) {
                int col = nBase + (ct0 + ci)*16 + m16;
                float bv = vb[col];
                int ct = col >> 4, n = col & 15;
                #pragma unroll
                for (int ri = 0; ri < 2; ri++)
                    #pragma unroll
                    for (int r = 0; r < 4; r++) {
                        int rr = mBase + (rt0 + ri)*16 + quad*4 + r;
                        int bb = rr >> 8, j = rr & 255;
                        int js = j >> 5, qv = (j >> 3) & 3, ev = j & 7;
                        float o = acc[ri][ci][r] + bv;
                        vtf[bb*65536 + (((ct*8 + js)*64 + n + 16*qv) << 3) + ev] = (_Float16)o;
                    }
            }
        } else {
            _Float16* OJ = (_Float16*)(ws + ((jobt == 1) ? WS_APJ : WS_BPJ));
            #pragma unroll
            for (int ci = 0; ci < 2; ci++) {
                int col = nBase + (ct0 + ci)*16 + m16;
                float bv = (jobt == 1) ? eb1[col] : 0.f;
                int ks = col >> 5, q = (col >> 3) & 3, e = col & 7;
                #pragma unroll
                for (int ri = 0; ri < 2; ri++)
                    #pragma unroll
                    for (int r = 0; r < 4; r++) {
                        int rr = mBase + (rt0 + ri)*16 + quad*4 + r;
                        if (rr < 1020) {
                            float o = acc[ri][ci][r] + bv;
                            int bb = rr / 255;
                            int j = rr - bb*255 + 1;
                            int jt = j >> 4, mm = j & 15;
                            OJ[bb*65536 + (((jt*8 + ks)*64 + mm + 16*q) << 3) + e] = (_Float16)o;
                            if (jobt == 1) ws[WS_AP + rr*256 + col] = o;
                        }
                    }
            }
        }
    } else if (blk < 208) {
        // qklog = nve @ fold (fold in Bf)
        {
            int d = tid;
            float f[16] = {0,0,0,0,0,0,0,0,0,0,0,0,0,0,0,0};
            for (int hd = 0; hd < 32; hd++) {
                float wq = aW[hd], wk = aW[32+hd];
                #pragma unroll
                for (int h = 0; h < 8; h++) {
                    f[h]   = fmaf(wq, qW[(h*32+hd)*256 + d], f[h]);
                    f[8+h] = fmaf(wk, kW[(h*32+hd)*256 + d], f[8+h]);
                }
            }
            int ksd = d >> 5, q2 = (d >> 3) & 3, jj = d & 7;
            #pragma unroll
            for (int n = 0; n < 16; n++)
                Bf[((ksd*64 + n + 16*q2))*8 + jj] = (_Float16)f[n];
        }
        __syncthreads();
        int mBase = (blk - 192)*64;
        f32x4 acc = {0.f,0.f,0.f,0.f};
        for (int k0 = 0; k0 < 256; k0 += 64) {
            half8 xa[2];
            #pragma unroll
            for (int hh = 0; hh < 2; hh++) {
                int kk = k0 + sko + hh*8;
                xa[hh] = cvt8(*(const float4*)&nve[(mBase + sr)*256 + kk],
                              *(const float4*)&nve[(mBase + sr)*256 + kk + 4]);
            }
            __syncthreads();
            #pragma unroll
            for (int hh = 0; hh < 2; hh++) {
                int krel = sko + hh*8;
                int c = krel >> 5, q2 = (krel >> 3) & 3;
                int ld = (sr & 15) + 16*q2, rt = sr >> 4;
                *(half8*)&Af[((rt*2 + c)*64 + ld)*8] = xa[hh];
            }
            __syncthreads();
            #pragma unroll
            for (int c = 0; c < 2; c++) {
                half8 A  = *(const half8*)&Af[((wave*2 + c)*64 + lane)*8];
                half8 Bv = *(const half8*)&Bf[(((k0 >> 5) + c)*64 + lane)*8];
                acc = __builtin_amdgcn_mfma_f32_16x16x32_f16(A, Bv, acc, 0,0,0);
            }
        }
        #pragma unroll
        for (int r = 0; r < 4; r++) {
            int rr = mBase + wave*16 + quad*4 + r;
            int bb = rr >> 8, tt2 = rr & 255;
            if (m16 < 8) ws[WS_QLOG + (bb*8 + m16)*256 + tt2] = acc[r];
            else         ws[WS_KLOG + (bb*8 + m16 - 8)*256 + tt2] = acc[r];
        }
    } else {
        // misc: MFG + CONST + zero j=0 frag rows
        _Float16* mfg = (_Float16*)(ws + WS_MFG);
        int k = tid;
        float a8[8] = {0,0,0,0,0,0,0,0};
        for (int hd = 0; hd < 32; hd++) {
            float we = aW[64+hd];
            #pragma unroll
            for (int h = 0; h < 8; h++)
                a8[h] = fmaf(we, eW2[(h*32+hd)*256 + k], a8[h]);
        }
        int ksd = k >> 5, q2 = (k >> 3) & 3, jj = k & 7;
        #pragma unroll
        for (int h = 0; h < 8; h++)
            mfg[((ksd*64 + h + 16*q2))*8 + jj] = (_Float16)a8[h];
        #pragma unroll
        for (int n = 8; n < 16; n++)
            mfg[((ksd*64 + n + 16*q2))*8 + jj] = (_Float16)0.f;
        {
            _Float16* apj = (_Float16*)(ws + WS_APJ);
            _Float16* bpj = (_Float16*)(ws + WS_BPJ);
            int ks0 = tid >> 5, qz = (tid >> 3) & 3, ez = tid & 7;
            int ad = ((ks0*64 + 16*qz) << 3) + ez;
            #pragma unroll
            for (int bb = 0; bb < 4; bb++) {
                apj[bb*65536 + ad] = (_Float16)0.f;
                bpj[bb*65536 + ad] = (_Float16)0.f;
            }
        }
        {   // CONST parallel: h = tid>>5, hd = tid&31, 32-lane shfl reduce
            int h = tid >> 5, hd = tid & 31;
            float c = aW[64+hd]*eb2[h*32+hd] + aW[hd]*qb[h*32+hd] + aW[32+hd]*kb[h*32+hd];
            #pragma unroll
            for (int off = 16; off >= 1; off >>= 1)
                c += __shfl_xor(c, off, 32);
            if (hd == 0) ws[WS_CONST + h] = c;
        }
    }
}

// ===========================================================================
// K3: 2 i-values per block. grid (128,4) x 512 threads (8 waves).
// Every bpj/vtf/mfg fragment load is used for both i's.
// ===========================================================================
__global__ __launch_bounds__(512, 4) void k3(
    const float* __restrict__ ln_g, const float* __restrict__ ln_b,
    const float* __restrict__ ab, const float* __restrict__ ws,
    float* __restrict__ out)
{
    const int b = blockIdx.y, gx = blockIdx.x;
    const int i0 = gx*2, i1 = gx*2 + 1;
    const int tid = threadIdx.x;
    const int wave = tid >> 6, lane = tid & 63;
    const int m16 = lane & 15, quad = lane >> 4;
    const bool sp = (gx == 0);   // i0 == 0 special

    __shared__ float klds[2048];
    __shared__ float PL0[8*PLS], PL1[8*PLS];
    __shared__ float gL[256], bL[256], aL0[256], aL1[256];
    __shared__ float2 st0[256], st1[256];
    __shared__ float stG0[256], stG1[256], stSB[256], stQB[256], stSA[256], stQA[256];
    __shared__ float baseh[16], sms[16], saqa[16];

    const half8 z8 = {(_Float16)0,(_Float16)0,(_Float16)0,(_Float16)0,
                      (_Float16)0,(_Float16)0,(_Float16)0,(_Float16)0};
    half8 ones8;
    #pragma unroll
    for (int e = 0; e < 8; e++) ones8[e] = (_Float16)1.0f;

    // ---- loads ----
    #pragma unroll
    for (int t = 0; t < 4; t++)
        klds[tid + t*512] = ws[WS_KLOG + b*2048 + tid + t*512];
    if (tid < 256) { gL[tid] = ln_g[tid]; bL[tid] = ln_b[tid]; }
    {
        int hf = tid >> 8, t8 = tid & 255;
        int ih = hf ? i1 : i0;
        float av = (ih >= 1) ? ws[WS_AP + ((size_t)(b*S + ih - 1))*256 + t8] : 0.f;
        (hf ? aL1 : aL0)[t8] = av;
        float s1 = av, s2 = av*av;
        #pragma unroll
        for (int off = 32; off >= 1; off >>= 1) {
            s1 += __shfl_xor(s1, off, 64);
            s2 += __shfl_xor(s2, off, 64);
        }
        int hw = wave >> 2, sub = wave & 3;
        if (lane == 0) { saqa[hw*8 + sub] = s1; saqa[hw*8 + 4 + sub] = s2; }
    }
    if (tid < 16) {
        int h = tid & 7, ih = (tid >> 3) ? i1 : i0;
        baseh[tid] = ws[WS_QLOG + (b*8+h)*256 + ih] + ab[0] + ws[WS_CONST + h];
    }
    __syncthreads();

    const _Float16* mfg = (const _Float16*)(ws + WS_MFG);
    const _Float16* bpj = (const _Float16*)(ws + WS_BPJ) + b*65536;
    const _Float16* apj = (const _Float16*)(ws + WS_APJ) + b*65536;
    const _Float16* vtf = (const _Float16*)(ws + WS_VTF) + b*65536;

    // ---- per-j stats via MFMA: wave handles tiles wave*2, wave*2+1 ----
    if (!sp) {
        #pragma unroll
        for (int t2 = 0; t2 < 2; t2++) {
            int tl = wave*2 + t2;
            f32x4 accGS = {}, accQB = {};
            #pragma unroll
            for (int ks = 0; ks < 8; ks++) {
                half8 bb = *(const half8*)&bpj[((tl*8+ks)*64 + lane) << 3];
                half8 ags;
                if (m16 == 0)
                    ags = cvt8(*(const float4*)&aL0[ks*32 + quad*8],
                               *(const float4*)&aL0[ks*32 + quad*8 + 4]);
                else if (m16 == 1)
                    ags = cvt8(*(const float4*)&aL1[ks*32 + quad*8],
                               *(const float4*)&aL1[ks*32 + quad*8 + 4]);
                else if (m16 == 2) ags = ones8;
                else ags = z8;
                accGS = __builtin_amdgcn_mfma_f32_16x16x32_f16(ags, bb, accGS, 0,0,0);
                accQB = __builtin_amdgcn_mfma_f32_16x16x32_f16(bb,  bb, accQB, 0,0,0);
            }
            int j = tl*16 + m16;
            if (quad == 0) { stG0[j] = accGS[0]; stG1[j] = accGS[1]; stSB[j] = accGS[2]; }
            if (quad == (m16 >> 2)) stQB[j] = accQB[m16 & 3];
        }
    } else {
        #pragma unroll
        for (int t2 = 0; t2 < 2; t2++) {
            int tl = wave*2 + t2;
            f32x4 accSB = {}, accSA = {}, accG = {}, accQA = {}, accQB = {}, accG1 = {};
            #pragma unroll
            for (int ks = 0; ks < 8; ks++) {
                int idx = ((tl*8+ks)*64 + lane) << 3;
                half8 bb = *(const half8*)&bpj[idx];
                half8 aa = *(const half8*)&apj[idx];
                half8 a1 = (m16 == 0) ? ones8 : z8;
                half8 ag1;
                if (m16 == 0)
                    ag1 = cvt8(*(const float4*)&aL1[ks*32 + quad*8],
                               *(const float4*)&aL1[ks*32 + quad*8 + 4]);
                else ag1 = z8;
                accSB = __builtin_amdgcn_mfma_f32_16x16x32_f16(a1, bb, accSB, 0,0,0);
                accSA = __builtin_amdgcn_mfma_f32_16x16x32_f16(a1, aa, accSA, 0,0,0);
                accG  = __builtin_amdgcn_mfma_f32_16x16x32_f16(aa, bb, accG,  0,0,0);
                accQA = __builtin_amdgcn_mfma_f32_16x16x32_f16(aa, aa, accQA, 0,0,0);
                accQB = __builtin_amdgcn_mfma_f32_16x16x32_f16(bb, bb, accQB, 0,0,0);
                accG1 = __builtin_amdgcn_mfma_f32_16x16x32_f16(ag1, bb, accG1, 0,0,0);
            }
            int j = tl*16 + m16;
            if (quad == 0) { stSB[j] = accSB[0]; stSA[j] = accSA[0]; stG1[j] = accG1[0]; }
            if (quad == (m16 >> 2)) {
                int r = m16 & 3;
                stG0[j] = accG[r]; stQA[j] = accQA[r]; stQB[j] = accQB[r];
            }
        }
    }
    __syncthreads();

    {   // per-(i,j) (inv, -mu*inv): thread = hf*256 + j
        int hf = tid >> 8, j = tid & 255;
        float2 v; v.x = 0.f; v.y = 0.f;
        if (j >= 1) {
            float sa, qa;
            if (sp && hf == 0) { sa = stSA[j]; qa = stQA[j]; }
            else {
                int base = hf ? 8 : 0;
                sa = saqa[base+0] + saqa[base+1] + saqa[base+2] + saqa[base+3];
                qa = saqa[base+4] + saqa[base+5] + saqa[base+6] + saqa[base+7];
            }
            float g = hf ? stG1[j] : stG0[j];
            float sb = stSB[j], qb2 = stQB[j];
            float mu  = (sa + sb) * (1.0f/256.0f);
            float var = (qa + qb2 + 2.f*g) * (1.0f/256.0f) - mu*mu;
            float inv = rsqrtf(var + 1e-5f);
            v.x = inv; v.y = -mu*inv;
        }
        (hf ? st1 : st0)[j] = v;
    }
    __syncthreads();

    // ---- logits MFMA: wave handles j-tiles wave*2, wave*2+1; both i ----
    f32x4 acc[2][2] = {};   // [i][tt2]
    float2 sv0[2], sv1[2];
    #pragma unroll
    for (int tt = 0; tt < 2; tt++) {
        sv0[tt] = st0[(wave*2 + tt)*16 + m16];
        sv1[tt] = st1[(wave*2 + tt)*16 + m16];
    }

    #pragma unroll
    for (int ks = 0; ks < 8; ks++) {
        int k = ks*32 + quad*8;
        float4 a00 = *(const float4*)&aL0[k], a01 = *(const float4*)&aL0[k+4];
        float4 a10 = *(const float4*)&aL1[k], a11 = *(const float4*)&aL1[k+4];
        float4 g0 = *(const float4*)&gL[k], g1 = *(const float4*)&gL[k+4];
        float4 b0 = *(const float4*)&bL[k], b1 = *(const float4*)&bL[k+4];
        half8 bf = *(const half8*)&mfg[(ks*64 + lane) << 3];
        float aa0[8] = {a00.x,a00.y,a00.z,a00.w,a01.x,a01.y,a01.z,a01.w};
        float aa1[8] = {a10.x,a10.y,a10.z,a10.w,a11.x,a11.y,a11.z,a11.w};
        float ga[8] = {g0.x,g0.y,g0.z,g0.w,g1.x,g1.y,g1.z,g1.w};
        float be[8] = {b0.x,b0.y,b0.z,b0.w,b1.x,b1.y,b1.z,b1.w};
        #pragma unroll
        for (int tt = 0; tt < 2; tt++) {
            int idx2 = ((((wave*2 + tt)*8 + ks)*64 + lane) << 3);
            half8 bp = *(const half8*)&bpj[idx2];
            half8 app = sp ? *(const half8*)&apj[idx2] : z8;
            half8 af0, af1;
            #pragma unroll
            for (int e = 0; e < 8; e++) {
                float bpe = (float)bp[e];
                float c0 = (sp ? (float)app[e] : aa0[e]) + bpe;
                float w0 = fmaf(fmaf(c0, sv0[tt].x, sv0[tt].y), ga[e], be[e]);
                af0[e] = (_Float16)fmaxf(w0, 0.f);
                float c1 = aa1[e] + bpe;
                float w1 = fmaf(fmaf(c1, sv1[tt].x, sv1[tt].y), ga[e], be[e]);
                af1[e] = (_Float16)fmaxf(w1, 0.f);
            }
            acc[0][tt] = __builtin_amdgcn_mfma_f32_16x16x32_f16(af0, bf, acc[0][tt], 0,0,0);
            acc[1][tt] = __builtin_amdgcn_mfma_f32_16x16x32_f16(af1, bf, acc[1][tt], 0,0,0);
        }
    }

    if (m16 < 8) {
        float basev0 = baseh[m16], basev1 = baseh[8 + m16];
        #pragma unroll
        for (int tt = 0; tt < 2; tt++)
            #pragma unroll
            for (int r = 0; r < 4; r++) {
                int jr = (wave*2 + tt)*16 + quad*4 + r;
                float kv = klds[m16*256 + jr];
                float v0 = basev0 + kv + ((jr == 0) ? -1e9f : acc[0][tt][r]);
                float v1 = basev1 + kv + ((jr == 0) ? -1e9f : acc[1][tt][r]);
                PL0[m16*PLS + jr] = v0;
                PL1[m16*PLS + jr] = v1;
            }
    }
    __syncthreads();

    // ---- softmax: wave w owns rows 2w, 2w+1 of 16 (row = i*8 + h) ----
    float* attnOut = out + 262144;
    #pragma unroll
    for (int hh = 0; hh < 2; hh++) {
        int row = wave*2 + hh;
        int ihf = row >> 3, h = row & 7;
        float* PLp = ihf ? PL1 : PL0;
        int iv = ihf ? i1 : i0;
        float4 v = *(const float4*)&PLp[h*PLS + lane*4];
        float mv = fmaxf(fmaxf(v.x, v.y), fmaxf(v.z, v.w));
        #pragma unroll
        for (int off = 32; off >= 1; off >>= 1)
            mv = fmaxf(mv, __shfl_xor(mv, off, 64));
        float4 p;
        p.x = __expf(v.x - mv); p.y = __expf(v.y - mv);
        p.z = __expf(v.z - mv); p.w = __expf(v.w - mv);
        float ss = p.x + p.y + p.z + p.w;
        #pragma unroll
        for (int off = 32; off >= 1; off >>= 1)
            ss += __shfl_xor(ss, off, 64);
        *(float4*)&PLp[h*PLS + lane*4] = p;
        if (lane == 0) sms[row] = ss;
        float rs = 1.0f / ss;
        float4 ao;
        ao.x = p.x*rs; ao.y = p.y*rs; ao.z = p.z*rs; ao.w = p.w*rs;
        *(float4*)&attnOut[((b*8+h)*256 + iv)*256 + lane*4] = ao;
    }
    __syncthreads();

    // ---- ctx via MFMA: wave handles col-tiles 2w, 2w+1; both i ----
    {
        f32x4 cacc[2][2] = {};   // [i][cl]
        int ct0 = wave*2;
        #pragma unroll
        for (int js = 0; js < 8; js++) {
            half8 af0, af1;
            if (m16 < 8) {
                float4 p00 = *(const float4*)&PL0[m16*PLS + js*32 + quad*8];
                float4 p01 = *(const float4*)&PL0[m16*PLS + js*32 + quad*8 + 4];
                af0 = cvt8(p00, p01);
                float4 p10 = *(const float4*)&PL1[m16*PLS + js*32 + quad*8];
                float4 p11 = *(const float4*)&PL1[m16*PLS + js*32 + quad*8 + 4];
                af1 = cvt8(p10, p11);
            } else { af0 = z8; af1 = z8; }
            #pragma unroll
            for (int cl = 0; cl < 2; cl++) {
                half8 bf = *(const half8*)&vtf[(((ct0+cl)*8 + js)*64 + lane) << 3];
                cacc[0][cl] = __builtin_amdgcn_mfma_f32_16x16x32_f16(af0, bf, cacc[0][cl], 0,0,0);
                cacc[1][cl] = __builtin_amdgcn_mfma_f32_16x16x32_f16(af1, bf, cacc[1][cl], 0,0,0);
            }
        }
        #pragma unroll
        for (int cl = 0; cl < 2; cl++) {
            int ct = ct0 + cl;
            int h = ct >> 1;
            if (quad == (h >> 2)) {
                out[(b*256 + i0)*256 + ct*16 + m16] = cacc[0][cl][h & 3] * (1.0f / sms[h]);
                out[(b*256 + i1)*256 + ct*16 + m16] = cacc[1][cl][h & 3] * (1.0f / sms[8 + h]);
            }
        }
    }
}

// ---------------------------------------------------------------------------
extern "C" void kernel_launch(void* const* d_in, const int* in_sizes, int n_in,
                              void* d_out, int out_size, void* d_ws, size_t ws_size,
                              hipStream_t stream)
{
    const float* desc = (const float*)d_in[0];
    const float* nve  = (const float*)d_in[1];
    const float* qW   = (const float*)d_in[2];
    const float* qb   = (const float*)d_in[3];
    const float* kW   = (const float*)d_in[4];
    const float* kb   = (const float*)d_in[5];
    const float* vW   = (const float*)d_in[6];
    const float* vb   = (const float*)d_in[7];
    const float* eW1  = (const float*)d_in[8];
    const float* eb1  = (const float*)d_in[9];
    const float* ln_g = (const float*)d_in[10];
    const float* ln_b = (const float*)d_in[11];
    const float* eW2  = (const float*)d_in[12];
    const float* eb2  = (const float*)d_in[13];
    const float* aW   = (const float*)d_in[14];
    const float* ab   = (const float*)d_in[15];
    float* ws  = (float*)d_ws;
    float* out = (float*)d_out;

    k1<<<dim3(209), 256, 0, stream>>>(desc, nve, qW, qb, kW, kb, vW, vb,
                                      eW1, eb1, eW2, eb2, aW, ws);
    k3<<<dim3(128, 4), 512, 0, stream>>>(ln_g, ln_b, ab, ws, out);
}